// Round 12
// baseline (152.543 us; speedup 1.0000x reference)
//
#include <hip/hip_runtime.h>
#include <hip/hip_bf16.h>

typedef unsigned long long ull;
typedef float nt_float4 __attribute__((ext_vector_type(4)));

#define B_ROWS 32768
#define D_COLS 2048
#define K_SEL  40
#define T_LO   1.74f          // P(x>1.74)=0.0409 -> C ~ 84 +- 9, in [40,128] at ~4.9 sigma
#define CAP    128            // 2 select-slots per lane
#define ALPHA_F  0.01f
#define TARGET_F 0.01953125f  // 40/2048 exact
#define G_COPIES 16           // histogram copies; multiple of 8 => XCD-local atomics

__device__ __forceinline__ ull fkey(float vv, unsigned col) {
    // monotone (value desc via max, index asc via ~col) 64-bit key
    unsigned bits = __float_as_uint(vv);
    unsigned sk = (bits & 0x80000000u) ? ~bits : (bits | 0x80000000u);
    return ((ull)sk << 32) | (ull)(unsigned)(~col);
}

__device__ __forceinline__ float f4elem(const float4& q, int j) {
    return j == 0 ? q.x : j == 1 ? q.y : j == 2 ? q.z : q.w;
}

// pack (val,col) into one 64-bit word: low = val bits, high = col
__device__ __forceinline__ ull pack_pair(float val, unsigned col) {
    return (ull)__float_as_uint(val) | ((ull)col << 32);
}

// Kernel 0: zero the privatized histograms (rocclr fillBuffer launches a tiny
// grid for small buffers; DIY at full BW).
__global__ __launch_bounds__(256) void kwta_zero_kernel(uint4* __restrict__ p) {
    p[blockIdx.x * 256 + threadIdx.x] = make_uint4(0u, 0u, 0u, 0u);
}

// Kernel 1: per-row exact top-K, one WAVE per row. R11/R12: (a) all write
// streams (row zeros, pairs) NON-TEMPORAL — the 256MB zero stream has zero
// reuse and was evicting x from the 256MB L3 (FETCH_SIZE = 131MB of a 256MB
// input re-fetched per replay); (b) full 8xfloat4 row residency — all 8 loads
// in flight, zero-stores issue under load latency, one compute phase.
template <bool FUSED>
__global__ __launch_bounds__(256) void kwta_topk_kernel(
        const float* __restrict__ x, float* __restrict__ out,
        unsigned* __restrict__ cnt, ull* __restrict__ pairs) {
    __shared__ float2 cands[4][CAP + 64];   // +64 per-lane trash slots

    const int lane = threadIdx.x & 63;
    const int wid  = threadIdx.x >> 6;
    const int row  = blockIdx.x * 4 + wid;
    const float* xr = x + (size_t)row * D_COLS;
    float* orow = out + (size_t)row * D_COLS;
    const ull lm_lt = (1ull << lane) - 1ull;
    float2* my = cands[wid];
    unsigned* mycnt_arr = cnt + ((size_t)(blockIdx.x & (G_COPIES - 1)) << 11);
    ull* prow = FUSED ? (pairs + (size_t)row * K_SEL) : nullptr;

    // ---- issue all 8 row loads (coalesced dwordx4, all in flight) ----
    float4 v[8];
#pragma unroll
    for (int s = 0; s < 8; ++s)
        v[s] = *reinterpret_cast<const float4*>(xr + s * 256 + lane * 4);

    if (FUSED) {
        // Non-temporal full-row zero: issues while the loads are in flight;
        // bypasses L3 so the write stream doesn't evict x.
        const nt_float4 z = {0.0f, 0.0f, 0.0f, 0.0f};
#pragma unroll
        for (int s = 0; s < 8; ++s)
            __builtin_nontemporal_store(z, reinterpret_cast<nt_float4*>(orow + s * 256) + lane);
    }

    // ---- per-lane candidate predicate mask (32 independent compares) ----
    unsigned m = 0;
#pragma unroll
    for (int s = 0; s < 8; ++s) {
#pragma unroll
        for (int j = 0; j < 4; ++j)
            m |= (f4elem(v[s], j) > T_LO ? 1u : 0u) << (s * 4 + j);
    }
    const unsigned mycnt = __popc(m);   // [0,32] -> 6 bits

    // ---- bit-plane ballot scan (6 independent ballots) ----
    unsigned base = 0, C = 0;
#pragma unroll
    for (int b = 0; b < 6; ++b) {
        ull bal = __ballot(((mycnt >> b) & 1u) != 0u);
        base += ((unsigned)__popcll(bal & lm_lt)) << b;
        C    += ((unsigned)__popcll(bal)) << b;
    }

    // ---- branchless LDS compaction ----
    {
        unsigned pos = base;
        const unsigned trash = CAP + (unsigned)lane;
#pragma unroll
        for (int s = 0; s < 8; ++s) {
#pragma unroll
            for (int j = 0; j < 4; ++j) {
                unsigned pred = (m >> (s * 4 + j)) & 1u;
                unsigned dst = pred ? pos : trash;
                dst = min(dst, (unsigned)(CAP + 63));
                my[dst] = make_float2(f4elem(v[s], j),
                    __uint_as_float((unsigned)(s * 256 + lane * 4 + j)));
                pos += pred;
            }
        }
    }

    if (C >= K_SEL && C <= CAP) {
        // ---- primary: early-exit bitwise radix select, 2 slots/lane ----
        float2 cd0 = my[lane];
        float2 cd1 = my[64 + lane];
        const bool ok0 = (unsigned)lane < C;
        const bool ok1 = (unsigned)(64 + lane) < C;
        const float    cv0 = ok0 ? cd0.x : 0.0f;
        const float    cv1 = ok1 ? cd1.x : 0.0f;
        const unsigned kb0 = __float_as_uint(cv0);  // >1.74 => positive => raw-bit order
        const unsigned kb1 = __float_as_uint(cv1);
        const unsigned cc0 = __float_as_uint(cd0.y);
        const unsigned cc1 = __float_as_uint(cd1.y);

        ull a0 = (C >= 64) ? ~0ull : ((1ull << C) - 1ull);
        ull a1 = (C <= 64) ? 0ull : ((C >= 128) ? ~0ull : ((1ull << (C - 64)) - 1ull));
        ull s0 = 0, s1 = 0;
        unsigned kk = K_SEL, na = C;

        if (na == kk) { s0 = a0; s1 = a1; kk = 0; }
        for (int b = 30; b >= 0 && kk; --b) {
            unsigned bit = 1u << b;
            ull b0 = __ballot((kb0 & bit) != 0) & a0;
            ull b1 = __ballot((kb1 & bit) != 0) & a1;
            unsigned cv = (unsigned)__popcll(b0) + (unsigned)__popcll(b1);
            if (cv >= kk) { a0 = b0; a1 = b1; na = cv; }
            else          { s0 |= b0; s1 |= b1; kk -= cv; a0 &= ~b0; a1 &= ~b1; na -= cv; }
            if (na == kk) { s0 |= a0; s1 |= a1; kk = 0; }
        }
        if (kk) {
            // bits exhausted: alive are exactly-equal values; take kk smallest cols
            ull e0 = a0, e1 = a1;
            for (unsigned t = 0; t < kk; ++t) {
                unsigned mymin = 0xFFFFFFFFu;
                if ((e0 >> lane) & 1ull) mymin = min(mymin, cc0);
                if ((e1 >> lane) & 1ull) mymin = min(mymin, cc1);
#pragma unroll
                for (int off = 32; off >= 1; off >>= 1)
                    mymin = min(mymin, (unsigned)__shfl_xor((int)mymin, off, 64));
                bool h0 = ((e0 >> lane) & 1ull) && cc0 == mymin;
                bool h1 = ((e1 >> lane) & 1ull) && cc1 == mymin;
                ull hb0 = __ballot(h0) & e0;
                ull hb1 = __ballot(h1) & e1;
                if (hb0) { s0 |= hb0 & (~hb0 + 1); e0 &= ~(hb0 & (~hb0 + 1)); }
                else     { s1 |= hb1 & (~hb1 + 1); e1 &= ~(hb1 & (~hb1 + 1)); }
            }
        }

        // ---- emit 40 packed pairs + counts ----
        unsigned n0 = (unsigned)__popcll(s0);
        if ((s0 >> lane) & 1ull) {
            unsigned p = (unsigned)__popcll(s0 & lm_lt);
            if (FUSED) __builtin_nontemporal_store(pack_pair(cv0, cc0), &prow[p]);
            else       reinterpret_cast<float2*>(orow)[p] = make_float2(cv0, __uint_as_float(cc0));
            atomicAdd(&mycnt_arr[cc0], 1u);
        }
        if ((s1 >> lane) & 1ull) {
            unsigned p = n0 + (unsigned)__popcll(s1 & lm_lt);
            if (FUSED) __builtin_nontemporal_store(pack_pair(cv1, cc1), &prow[p]);
            else       reinterpret_cast<float2*>(orow)[p] = make_float2(cv1, __uint_as_float(cc1));
            atomicAdd(&mycnt_arr[cc1], 1u);
        }
    } else {
        // ---- fully general fallback (statistically never for N(0,1) data):
        //      K exact wave-argmax rounds over the in-register row
        unsigned rm = 0;
        for (int t = 0; t < K_SEL; ++t) {
            ull best = 0;
#pragma unroll
            for (int s = 0; s < 8; ++s) {
#pragma unroll
                for (int j = 0; j < 4; ++j) {
                    int slot = s * 4 + j;
                    if (!((rm >> slot) & 1u)) {
                        ull key = fkey(f4elem(v[s], j), (unsigned)(s * 256 + lane * 4 + j));
                        best = best > key ? best : key;
                    }
                }
            }
#pragma unroll
            for (int off = 32; off >= 1; off >>= 1) {
                ull o = __shfl_xor(best, off, 64);
                best = best > o ? best : o;
            }
#pragma unroll
            for (int s = 0; s < 8; ++s) {
#pragma unroll
                for (int j = 0; j < 4; ++j) {
                    int slot = s * 4 + j;
                    unsigned col = (unsigned)(s * 256 + lane * 4 + j);
                    if (!((rm >> slot) & 1u) && fkey(f4elem(v[s], j), col) == best) {
                        rm |= 1u << slot;
                        if (FUSED) prow[t] = pack_pair(f4elem(v[s], j), col);
                        else       reinterpret_cast<float2*>(orow)[t] =
                                       make_float2(f4elem(v[s], j), __uint_as_float(col));
                        atomicAdd(&mycnt_arr[col], 1u);
                    }
                }
            }
        }
    }
}

// Kernel 2: sum 16 histogram copies; boost[d] = exp(-(duty*0.99 + 0.01*cnt/B
// - target)). 16 blocks x 128 threads: readers spread over all XCDs.
__global__ __launch_bounds__(128) void kwta_boost_kernel(
        const float* __restrict__ duty, const unsigned* __restrict__ cnt,
        float* __restrict__ boost) {
    int d = blockIdx.x * 128 + threadIdx.x;
    unsigned s = 0;
#pragma unroll
    for (int g = 0; g < G_COPIES; ++g) s += cnt[((size_t)g << 11) + d];
    float mean = (float)s * (1.0f / 32768.0f);
    float nd = duty[d] * (1.0f - ALPHA_F) + ALPHA_F * mean;
    boost[d] = expf(-(nd - TARGET_F));
}

// Kernel 3 (fused path): one thread per (row,k) pair — overwrite the selected
// slot with val*boost[col]. Streaming accesses non-temporal; boost (8KB)
// stays cache-hot.
__global__ __launch_bounds__(256) void kwta_fixup_kernel(
        float* __restrict__ out, const ull* __restrict__ pairs,
        const float* __restrict__ boost) {
    const int gid = blockIdx.x * 256 + threadIdx.x;
    const ull pr = __builtin_nontemporal_load(&pairs[gid]);
    const float val = __uint_as_float((unsigned)(pr & 0xFFFFFFFFull));
    const unsigned col = (unsigned)(pr >> 32);
    const int row = gid / K_SEL;
    __builtin_nontemporal_store(val * boost[col], &out[(size_t)row * D_COLS + col]);
}

// Kernel 3 (legacy path): block-per-row scatter via LDS (used only if ws_size
// can't hold the pairs buffer).
__global__ __launch_bounds__(256) void kwta_scatter_kernel(
        float* __restrict__ out, const float* __restrict__ boost) {
    __shared__ float buf[D_COLS];
    const int t = threadIdx.x;
    const size_t rb = (size_t)blockIdx.x * D_COLS;

    float2 pr = make_float2(0.0f, 0.0f);
    if (t < K_SEL) pr = reinterpret_cast<const float2*>(out + rb)[t];

    float4 z = make_float4(0.0f, 0.0f, 0.0f, 0.0f);
    reinterpret_cast<float4*>(buf)[t * 2]     = z;
    reinterpret_cast<float4*>(buf)[t * 2 + 1] = z;
    __syncthreads();

    if (t < K_SEL) {
        unsigned col = __float_as_uint(pr.y);
        buf[col] = pr.x * boost[col];
    }
    __syncthreads();

    reinterpret_cast<float4*>(out + rb)[t * 2]     = reinterpret_cast<const float4*>(buf)[t * 2];
    reinterpret_cast<float4*>(out + rb)[t * 2 + 1] = reinterpret_cast<const float4*>(buf)[t * 2 + 1];
}

extern "C" void kernel_launch(void* const* d_in, const int* in_sizes, int n_in,
                              void* d_out, int out_size, void* d_ws, size_t ws_size,
                              hipStream_t stream) {
    const float* x    = (const float*)d_in[0];
    const float* duty = (const float*)d_in[1];
    float* out = (float*)d_out;

    const size_t CNT_BYTES   = (size_t)G_COPIES * 8192;          // 128 KB
    const size_t PAIRS_BYTES = (size_t)B_ROWS * K_SEL * 8;       // 10.49 MB

    unsigned* cnt   = (unsigned*)d_ws;
    float*    boost = (float*)((char*)d_ws + CNT_BYTES);
    ull*      pairs = (ull*)((char*)d_ws + CNT_BYTES + 8192);

    const bool fused = ws_size >= CNT_BYTES + 8192 + PAIRS_BYTES;

    // zero the 128KB of histograms
    kwta_zero_kernel<<<CNT_BYTES / 4096, 256, 0, stream>>>((uint4*)d_ws);

    if (fused) {
        kwta_topk_kernel<true><<<B_ROWS / 4, 256, 0, stream>>>(x, out, cnt, pairs);
        kwta_boost_kernel<<<D_COLS / 128, 128, 0, stream>>>(duty, cnt, boost);
        kwta_fixup_kernel<<<B_ROWS * K_SEL / 256, 256, 0, stream>>>(out, pairs, boost);
    } else {
        kwta_topk_kernel<false><<<B_ROWS / 4, 256, 0, stream>>>(x, out, cnt, nullptr);
        kwta_boost_kernel<<<D_COLS / 128, 128, 0, stream>>>(duty, cnt, boost);
        kwta_scatter_kernel<<<B_ROWS, 256, 0, stream>>>(out, boost);
    }
}

// Round 13
// 148.014 us; speedup vs baseline: 1.0306x; 1.0306x over previous
//
#include <hip/hip_runtime.h>
#include <hip/hip_bf16.h>

typedef unsigned long long ull;
typedef float nt_float4 __attribute__((ext_vector_type(4)));

#define B_ROWS 32768
#define D_COLS 2048
#define K_SEL  40
#define T_LO   1.74f          // P(x>1.74)=0.0409 -> C ~ 84 +- 9, in [40,128] at ~4.9 sigma
#define CAP    128            // 2 select-slots per lane
#define ALPHA_F  0.01f
#define TARGET_F 0.01953125f  // 40/2048 exact
#define G_COPIES 16           // histogram copies; multiple of 8 => XCD-local atomics
#define ROWS_PER_WAVE 4

__device__ __forceinline__ ull fkey(float vv, unsigned col) {
    // monotone (value desc via max, index asc via ~col) 64-bit key
    unsigned bits = __float_as_uint(vv);
    unsigned sk = (bits & 0x80000000u) ? ~bits : (bits | 0x80000000u);
    return ((ull)sk << 32) | (ull)(unsigned)(~col);
}

__device__ __forceinline__ float f4elem(const float4& q, int j) {
    return j == 0 ? q.x : j == 1 ? q.y : j == 2 ? q.z : q.w;
}

// pack (val,col) into one 64-bit word: low = val bits, high = col
__device__ __forceinline__ ull pack_pair(float val, unsigned col) {
    return (ull)__float_as_uint(val) | ((ull)col << 32);
}

// Kernel 0: zero the privatized histograms (rocclr fillBuffer launches a tiny
// grid for small buffers; DIY at full BW).
__global__ __launch_bounds__(256) void kwta_zero_kernel(uint4* __restrict__ p) {
    p[blockIdx.x * 256 + threadIdx.x] = make_uint4(0u, 0u, 0u, 0u);
}

__device__ __forceinline__ void load_row(float4 (&v)[8], const float* xr, int lane) {
#pragma unroll
    for (int s = 0; s < 8; ++s)
        v[s] = *reinterpret_cast<const float4*>(xr + s * 256 + lane * 4);
}

// Process one row already resident in registers: zero-write the output row,
// threshold-compact candidates to wave-private LDS, exact bitwise radix
// select of the top-40, emit packed pairs + histogram counts.
template <bool FUSED>
__device__ __forceinline__ void process_row(
        const float4 (&v)[8], int row, int lane, float2* __restrict__ my,
        float* __restrict__ out, unsigned* __restrict__ mycnt_arr,
        ull* __restrict__ pairs) {
    const ull lm_lt = (1ull << lane) - 1ull;
    float* orow = out + (size_t)row * D_COLS;
    ull* prow = FUSED ? (pairs + (size_t)row * K_SEL) : nullptr;

    if (FUSED) {
        // Non-temporal full-row zero (no reuse; don't displace x in caches).
        const nt_float4 z = {0.0f, 0.0f, 0.0f, 0.0f};
#pragma unroll
        for (int s = 0; s < 8; ++s)
            __builtin_nontemporal_store(z, reinterpret_cast<nt_float4*>(orow + s * 256) + lane);
    }

    // ---- per-lane candidate predicate mask (32 independent compares) ----
    unsigned m = 0;
#pragma unroll
    for (int s = 0; s < 8; ++s) {
#pragma unroll
        for (int j = 0; j < 4; ++j)
            m |= (f4elem(v[s], j) > T_LO ? 1u : 0u) << (s * 4 + j);
    }
    const unsigned mycnt = __popc(m);   // [0,32] -> 6 bits

    // ---- bit-plane ballot scan (6 independent ballots) ----
    unsigned base = 0, C = 0;
#pragma unroll
    for (int b = 0; b < 6; ++b) {
        ull bal = __ballot(((mycnt >> b) & 1u) != 0u);
        base += ((unsigned)__popcll(bal & lm_lt)) << b;
        C    += ((unsigned)__popcll(bal)) << b;
    }

    // ---- branchless LDS compaction ----
    {
        unsigned pos = base;
        const unsigned trash = CAP + (unsigned)lane;
#pragma unroll
        for (int s = 0; s < 8; ++s) {
#pragma unroll
            for (int j = 0; j < 4; ++j) {
                unsigned pred = (m >> (s * 4 + j)) & 1u;
                unsigned dst = pred ? pos : trash;
                dst = min(dst, (unsigned)(CAP + 63));
                my[dst] = make_float2(f4elem(v[s], j),
                    __uint_as_float((unsigned)(s * 256 + lane * 4 + j)));
                pos += pred;
            }
        }
    }

    if (C >= K_SEL && C <= CAP) {
        // ---- primary: early-exit bitwise radix select, 2 slots/lane ----
        float2 cd0 = my[lane];
        float2 cd1 = my[64 + lane];
        const bool ok0 = (unsigned)lane < C;
        const bool ok1 = (unsigned)(64 + lane) < C;
        const float    cv0 = ok0 ? cd0.x : 0.0f;
        const float    cv1 = ok1 ? cd1.x : 0.0f;
        const unsigned kb0 = __float_as_uint(cv0);  // >1.74 => positive => raw-bit order
        const unsigned kb1 = __float_as_uint(cv1);
        const unsigned cc0 = __float_as_uint(cd0.y);
        const unsigned cc1 = __float_as_uint(cd1.y);

        ull a0 = (C >= 64) ? ~0ull : ((1ull << C) - 1ull);
        ull a1 = (C <= 64) ? 0ull : ((C >= 128) ? ~0ull : ((1ull << (C - 64)) - 1ull));
        ull s0 = 0, s1 = 0;
        unsigned kk = K_SEL, na = C;

        if (na == kk) { s0 = a0; s1 = a1; kk = 0; }
        for (int b = 30; b >= 0 && kk; --b) {
            unsigned bit = 1u << b;
            ull b0 = __ballot((kb0 & bit) != 0) & a0;
            ull b1 = __ballot((kb1 & bit) != 0) & a1;
            unsigned cv = (unsigned)__popcll(b0) + (unsigned)__popcll(b1);
            if (cv >= kk) { a0 = b0; a1 = b1; na = cv; }
            else          { s0 |= b0; s1 |= b1; kk -= cv; a0 &= ~b0; a1 &= ~b1; na -= cv; }
            if (na == kk) { s0 |= a0; s1 |= a1; kk = 0; }
        }
        if (kk) {
            // bits exhausted: alive are exactly-equal values; take kk smallest cols
            ull e0 = a0, e1 = a1;
            for (unsigned t = 0; t < kk; ++t) {
                unsigned mymin = 0xFFFFFFFFu;
                if ((e0 >> lane) & 1ull) mymin = min(mymin, cc0);
                if ((e1 >> lane) & 1ull) mymin = min(mymin, cc1);
#pragma unroll
                for (int off = 32; off >= 1; off >>= 1)
                    mymin = min(mymin, (unsigned)__shfl_xor((int)mymin, off, 64));
                bool h0 = ((e0 >> lane) & 1ull) && cc0 == mymin;
                bool h1 = ((e1 >> lane) & 1ull) && cc1 == mymin;
                ull hb0 = __ballot(h0) & e0;
                ull hb1 = __ballot(h1) & e1;
                if (hb0) { s0 |= hb0 & (~hb0 + 1); e0 &= ~(hb0 & (~hb0 + 1)); }
                else     { s1 |= hb1 & (~hb1 + 1); e1 &= ~(hb1 & (~hb1 + 1)); }
            }
        }

        // ---- emit 40 packed pairs + counts (XCD-local histogram copy) ----
        unsigned n0 = (unsigned)__popcll(s0);
        if ((s0 >> lane) & 1ull) {
            unsigned p = (unsigned)__popcll(s0 & lm_lt);
            if (FUSED) __builtin_nontemporal_store(pack_pair(cv0, cc0), &prow[p]);
            else       reinterpret_cast<float2*>(orow)[p] = make_float2(cv0, __uint_as_float(cc0));
            atomicAdd(&mycnt_arr[cc0], 1u);
        }
        if ((s1 >> lane) & 1ull) {
            unsigned p = n0 + (unsigned)__popcll(s1 & lm_lt);
            if (FUSED) __builtin_nontemporal_store(pack_pair(cv1, cc1), &prow[p]);
            else       reinterpret_cast<float2*>(orow)[p] = make_float2(cv1, __uint_as_float(cc1));
            atomicAdd(&mycnt_arr[cc1], 1u);
        }
    } else {
        // ---- fully general fallback (statistically never for N(0,1) data):
        //      K exact wave-argmax rounds over the in-register row
        unsigned rm = 0;
        for (int t = 0; t < K_SEL; ++t) {
            ull best = 0;
#pragma unroll
            for (int s = 0; s < 8; ++s) {
#pragma unroll
                for (int j = 0; j < 4; ++j) {
                    int slot = s * 4 + j;
                    if (!((rm >> slot) & 1u)) {
                        ull key = fkey(f4elem(v[s], j), (unsigned)(s * 256 + lane * 4 + j));
                        best = best > key ? best : key;
                    }
                }
            }
#pragma unroll
            for (int off = 32; off >= 1; off >>= 1) {
                ull o = __shfl_xor(best, off, 64);
                best = best > o ? best : o;
            }
#pragma unroll
            for (int s = 0; s < 8; ++s) {
#pragma unroll
                for (int j = 0; j < 4; ++j) {
                    int slot = s * 4 + j;
                    unsigned col = (unsigned)(s * 256 + lane * 4 + j);
                    if (!((rm >> slot) & 1u) && fkey(f4elem(v[s], j), col) == best) {
                        rm |= 1u << slot;
                        if (FUSED) prow[t] = pack_pair(f4elem(v[s], j), col);
                        else       reinterpret_cast<float2*>(orow)[t] =
                                       make_float2(f4elem(v[s], j), __uint_as_float(col));
                        atomicAdd(&mycnt_arr[col], 1u);
                    }
                }
            }
        }
    }
}

// Kernel 1: per-row exact top-K, 4 ROWS PER WAVE, software-pipelined: while
// row r's select phase walks its serially-dependent ballot chains, row r+1's
// 8 dwordx4 loads are in flight. Two named register buffers (static indexing).
template <bool FUSED>
__global__ __launch_bounds__(256) void kwta_topk_kernel(
        const float* __restrict__ x, float* __restrict__ out,
        unsigned* __restrict__ cnt, ull* __restrict__ pairs) {
    __shared__ float2 cands[4][CAP + 64];   // per-wave region (+64 trash slots)

    const int lane = threadIdx.x & 63;
    const int wid  = threadIdx.x >> 6;
    const int rbase = (blockIdx.x * 4 + wid) * ROWS_PER_WAVE;
    float2* my = cands[wid];
    unsigned* mycnt_arr = cnt + ((size_t)(blockIdx.x & (G_COPIES - 1)) << 11);

    float4 A[8], B[8];
    load_row(A, x + (size_t)(rbase + 0) * D_COLS, lane);

    load_row(B, x + (size_t)(rbase + 1) * D_COLS, lane);      // prefetch r1
    process_row<FUSED>(A, rbase + 0, lane, my, out, mycnt_arr, pairs);

    load_row(A, x + (size_t)(rbase + 2) * D_COLS, lane);      // prefetch r2
    process_row<FUSED>(B, rbase + 1, lane, my, out, mycnt_arr, pairs);

    load_row(B, x + (size_t)(rbase + 3) * D_COLS, lane);      // prefetch r3
    process_row<FUSED>(A, rbase + 2, lane, my, out, mycnt_arr, pairs);

    process_row<FUSED>(B, rbase + 3, lane, my, out, mycnt_arr, pairs);
}

// Kernel 2: sum 16 histogram copies; boost[d] = exp(-(duty*0.99 + 0.01*cnt/B
// - target)). 16 blocks x 128 threads: readers spread over all XCDs.
__global__ __launch_bounds__(128) void kwta_boost_kernel(
        const float* __restrict__ duty, const unsigned* __restrict__ cnt,
        float* __restrict__ boost) {
    int d = blockIdx.x * 128 + threadIdx.x;
    unsigned s = 0;
#pragma unroll
    for (int g = 0; g < G_COPIES; ++g) s += cnt[((size_t)g << 11) + d];
    float mean = (float)s * (1.0f / 32768.0f);
    float nd = duty[d] * (1.0f - ALPHA_F) + ALPHA_F * mean;
    boost[d] = expf(-(nd - TARGET_F));
}

// Kernel 3 (fused path): one thread per (row,k) pair — overwrite the selected
// slot with val*boost[col]. Streaming accesses non-temporal; boost cache-hot.
__global__ __launch_bounds__(256) void kwta_fixup_kernel(
        float* __restrict__ out, const ull* __restrict__ pairs,
        const float* __restrict__ boost) {
    const int gid = blockIdx.x * 256 + threadIdx.x;
    const ull pr = __builtin_nontemporal_load(&pairs[gid]);
    const float val = __uint_as_float((unsigned)(pr & 0xFFFFFFFFull));
    const unsigned col = (unsigned)(pr >> 32);
    const int row = gid / K_SEL;
    __builtin_nontemporal_store(val * boost[col], &out[(size_t)row * D_COLS + col]);
}

// Kernel 3 (legacy path): block-per-row scatter via LDS (used only if ws_size
// can't hold the pairs buffer).
__global__ __launch_bounds__(256) void kwta_scatter_kernel(
        float* __restrict__ out, const float* __restrict__ boost) {
    __shared__ float buf[D_COLS];
    const int t = threadIdx.x;
    const size_t rb = (size_t)blockIdx.x * D_COLS;

    float2 pr = make_float2(0.0f, 0.0f);
    if (t < K_SEL) pr = reinterpret_cast<const float2*>(out + rb)[t];

    float4 z = make_float4(0.0f, 0.0f, 0.0f, 0.0f);
    reinterpret_cast<float4*>(buf)[t * 2]     = z;
    reinterpret_cast<float4*>(buf)[t * 2 + 1] = z;
    __syncthreads();

    if (t < K_SEL) {
        unsigned col = __float_as_uint(pr.y);
        buf[col] = pr.x * boost[col];
    }
    __syncthreads();

    reinterpret_cast<float4*>(out + rb)[t * 2]     = reinterpret_cast<const float4*>(buf)[t * 2];
    reinterpret_cast<float4*>(out + rb)[t * 2 + 1] = reinterpret_cast<const float4*>(buf)[t * 2 + 1];
}

extern "C" void kernel_launch(void* const* d_in, const int* in_sizes, int n_in,
                              void* d_out, int out_size, void* d_ws, size_t ws_size,
                              hipStream_t stream) {
    const float* x    = (const float*)d_in[0];
    const float* duty = (const float*)d_in[1];
    float* out = (float*)d_out;

    const size_t CNT_BYTES   = (size_t)G_COPIES * 8192;          // 128 KB
    const size_t PAIRS_BYTES = (size_t)B_ROWS * K_SEL * 8;       // 10.49 MB

    unsigned* cnt   = (unsigned*)d_ws;
    float*    boost = (float*)((char*)d_ws + CNT_BYTES);
    ull*      pairs = (ull*)((char*)d_ws + CNT_BYTES + 8192);

    const bool fused = ws_size >= CNT_BYTES + 8192 + PAIRS_BYTES;

    // zero the 128KB of histograms
    kwta_zero_kernel<<<CNT_BYTES / 4096, 256, 0, stream>>>((uint4*)d_ws);

    if (fused) {
        kwta_topk_kernel<true><<<B_ROWS / 4 / ROWS_PER_WAVE, 256, 0, stream>>>(x, out, cnt, pairs);
        kwta_boost_kernel<<<D_COLS / 128, 128, 0, stream>>>(duty, cnt, boost);
        kwta_fixup_kernel<<<B_ROWS * K_SEL / 256, 256, 0, stream>>>(out, pairs, boost);
    } else {
        kwta_topk_kernel<false><<<B_ROWS / 4 / ROWS_PER_WAVE, 256, 0, stream>>>(x, out, cnt, nullptr);
        kwta_boost_kernel<<<D_COLS / 128, 128, 0, stream>>>(duty, cnt, boost);
        kwta_scatter_kernel<<<B_ROWS, 256, 0, stream>>>(out, boost);
    }
}